// Round 1
// baseline (83.209 us; speedup 1.0000x reference)
//
#include <hip/hip_runtime.h>

#define DSZ 128
#define TX 16
#define TY 16
#define TZ 16
#define PX 24        // TX + 8 halo
#define PY 24        // TY + 8 halo
#define NPL 24       // TZ + 8 halo
#define NVOX 4194304.0f

__global__ void ncc_zero(float* out) { out[0] = 0.0f; }

__global__ __launch_bounds__(256) void ncc_main(const float* __restrict__ Iin,
                                                const float* __restrict__ Jin,
                                                float* __restrict__ out)
{
    const int tx0 = blockIdx.x * TX;
    const int ty0 = blockIdx.y * TY;
    const int b   = blockIdx.z >> 3;
    const int tz0 = (blockIdx.z & 7) * TZ;
    const int tid = threadIdx.x;
    const int lx  = tid & 15;
    const int ly  = tid >> 4;

    const float* __restrict__ Ib = Iin + b * (DSZ * DSZ * DSZ);
    const float* __restrict__ Jb = Jin + b * (DSZ * DSZ * DSZ);

    // +1 padding on leading dims breaks power-of-2 bank strides
    __shared__ float sI[PY][PX + 1];
    __shared__ float sJ[PY][PX + 1];
    __shared__ float s0[PY][TX + 1];  // sum I
    __shared__ float s1[PY][TX + 1];  // sum J
    __shared__ float s2[PY][TX + 1];  // sum I*I
    __shared__ float s3[PY][TX + 1];  // sum J*J
    __shared__ float s4[PY][TX + 1];  // sum I*J

    // 9-plane rolling window, registers only (all indices compile-time)
    float rb0[9], rb1[9], rb2[9], rb3[9], rb4[9];
#pragma unroll
    for (int i = 0; i < 9; ++i) { rb0[i]=0.f; rb1[i]=0.f; rb2[i]=0.f; rb3[i]=0.f; rb4[i]=0.f; }
    float zs0=0.f, zs1=0.f, zs2=0.f, zs3=0.f, zs4=0.f;
    float acc = 0.f;

    for (int zi = 0; zi < NPL; ++zi) {
        const int zp = tz0 + zi - 4;
        const bool zvalid = ((unsigned)zp < (unsigned)DSZ);

        // stage halo'd plane (zero-padded) into LDS
        for (int it = tid; it < PY * PX; it += 256) {
            const int r  = it / PX;
            const int c  = it - r * PX;
            const int gy = ty0 + r - 4;
            const int gx = tx0 + c - 4;
            float vi = 0.f, vj = 0.f;
            if (zvalid && (unsigned)gy < (unsigned)DSZ && (unsigned)gx < (unsigned)DSZ) {
                const int idx = (zp * DSZ + gy) * DSZ + gx;
                vi = Ib[idx];
                vj = Jb[idx];
            }
            sI[r][c] = vi;
            sJ[r][c] = vj;
        }
        __syncthreads();

        // x-pass: 9-tap sums of the 5 moments along x
        for (int it = tid; it < PY * TX; it += 256) {
            const int r = it >> 4;
            const int x = it & 15;
            float a=0.f, bq=0.f, aa=0.f, bb=0.f, ab=0.f;
#pragma unroll
            for (int dx = 0; dx < 9; ++dx) {
                const float vi = sI[r][x + dx];
                const float vj = sJ[r][x + dx];
                a += vi; bq += vj;
                aa = fmaf(vi, vi, aa);
                bb = fmaf(vj, vj, bb);
                ab = fmaf(vi, vj, ab);
            }
            s0[r][x] = a; s1[r][x] = bq; s2[r][x] = aa; s3[r][x] = bb; s4[r][x] = ab;
        }
        __syncthreads();

        // y-pass: 9-tap along y, one output column per thread
        float y0=0.f, y1=0.f, y2=0.f, y3=0.f, y4=0.f;
#pragma unroll
        for (int dy = 0; dy < 9; ++dy) {
            y0 += s0[ly + dy][lx];
            y1 += s1[ly + dy][lx];
            y2 += s2[ly + dy][lx];
            y3 += s3[ly + dy][lx];
            y4 += s4[ly + dy][lx];
        }

        // rolling z-window update
        zs0 += y0 - rb0[0]; zs1 += y1 - rb1[0]; zs2 += y2 - rb2[0];
        zs3 += y3 - rb3[0]; zs4 += y4 - rb4[0];
#pragma unroll
        for (int i = 0; i < 8; ++i) {
            rb0[i]=rb0[i+1]; rb1[i]=rb1[i+1]; rb2[i]=rb2[i+1]; rb3[i]=rb3[i+1]; rb4[i]=rb4[i+1];
        }
        rb0[8]=y0; rb1[8]=y1; rb2[8]=y2; rb3[8]=y3; rb4[8]=y4;

        if (zi >= 8) {
            // voxel (b, tz0+zi-8, ty0+ly, tx0+lx) complete; reference formulas verbatim
            const float inv = 1.0f / 729.0f;
            const float uI = zs0 * inv;
            const float uJ = zs1 * inv;
            const float cross = zs4 - uJ * zs0 - uI * zs1 + uI * uJ * 729.0f;
            const float Ivar  = zs2 - 2.0f * uI * zs0 + uI * uI * 729.0f;
            const float Jvar  = zs3 - 2.0f * uJ * zs1 + uJ * uJ * 729.0f;
            const float cc = cross * cross / (Ivar * Jvar + 1e-5f);
            acc += cc;
        }
    }

    // block reduction: wave shuffle then cross-wave via LDS
#pragma unroll
    for (int off = 32; off > 0; off >>= 1) acc += __shfl_down(acc, off);
    __shared__ float wpart[4];
    if ((tid & 63) == 0) wpart[tid >> 6] = acc;
    __syncthreads();
    if (tid == 0) {
        const float s = wpart[0] + wpart[1] + wpart[2] + wpart[3];
        atomicAdd(out, s * (-1.0f / NVOX));
    }
}

extern "C" void kernel_launch(void* const* d_in, const int* in_sizes, int n_in,
                              void* d_out, int out_size, void* d_ws, size_t ws_size,
                              hipStream_t stream)
{
    // setup_inputs order: d_in[0] = y_pred (J), d_in[1] = y_true (I)
    const float* J = (const float*)d_in[0];
    const float* I = (const float*)d_in[1];
    float* out = (float*)d_out;

    ncc_zero<<<dim3(1), dim3(1), 0, stream>>>(out);
    dim3 grid(DSZ / TX, DSZ / TY, 2 * (DSZ / TZ));  // 8 x 8 x 16 = 1024 blocks
    ncc_main<<<grid, dim3(256), 0, stream>>>(I, J, out);
}

// Round 2
// 61.779 us; speedup vs baseline: 1.3469x; 1.3469x over previous
//
#include <hip/hip_runtime.h>

#define DSZ 128
#define TX 16
#define TY 16
#define PY 24            // TY + 8 halo
#define NVOX 4194304.0f

__global__ void ncc_zero(float* out) { out[0] = 0.0f; }

__global__ __launch_bounds__(256) void ncc_main(const float* __restrict__ Iin,
                                                const float* __restrict__ Jin,
                                                float* __restrict__ out)
{
    const int tx0 = blockIdx.x * TX;
    const int ty0 = blockIdx.y * TY;
    const int b   = blockIdx.z >> 3;
    const int tz0 = (blockIdx.z & 7) * 16;
    const int tid = threadIdx.x;
    const int lx  = tid & 15;
    const int ly  = tid >> 4;

    const float* __restrict__ Ib = Iin + b * (DSZ * DSZ * DSZ);
    const float* __restrict__ Jb = Jin + b * (DSZ * DSZ * DSZ);

    // I,J interleaved as float2; row stride 26*8=208B (16B-aligned, 52-word
    // bank stride -> conflict-free b64/b128 patterns). Two plane buffers.
    __shared__ float2 sIJ[2][PY][26];
    // moments: (sumI,sumJ,sumII,sumJJ) as float4 + sumIJ scalar; stride 17 (odd)
    __shared__ float4 s4m[2][PY][17];
    __shared__ float  s1m[2][PY][17];

    // 9-plane rolling z-window, registers only (compile-time indices)
    float rb0[9], rb1[9], rb2[9], rb3[9], rb4[9];
#pragma unroll
    for (int i = 0; i < 9; ++i) { rb0[i]=0.f; rb1[i]=0.f; rb2[i]=0.f; rb3[i]=0.f; rb4[i]=0.f; }
    float zs0=0.f, zs1=0.f, zs2=0.f, zs3=0.f, zs4=0.f;
    float acc = 0.f;

    for (int rnd = 0; rnd < 12; ++rnd) {
        // ---- stage two halo'd planes (zero-padded), float2-paired loads ----
#pragma unroll
        for (int p = 0; p < 2; ++p) {
            const int zp = tz0 + 2 * rnd + p - 4;
            const bool zvalid = ((unsigned)zp < (unsigned)DSZ);
            for (int it = tid; it < PY * 12; it += 256) {
                const int r = it / 12;
                const int c = it - r * 12;
                const int gy = ty0 + r - 4;
                const int gx = tx0 + 2 * c - 4;      // even by construction
                float4 w = make_float4(0.f, 0.f, 0.f, 0.f);
                if (zvalid && (unsigned)gy < (unsigned)DSZ && (unsigned)gx < (unsigned)(DSZ - 1)) {
                    const int idx = (zp * DSZ + gy) * DSZ + gx;
                    const float2 vi = *(const float2*)(Ib + idx);
                    const float2 vj = *(const float2*)(Jb + idx);
                    w = make_float4(vi.x, vj.x, vi.y, vj.y);
                }
                *(float4*)&sIJ[p][r][2 * c] = w;     // 16B-aligned (208%16==0)
            }
        }
        __syncthreads();

        // ---- x-pass: 9-tap b64 reads, b128+b32 writes, both planes ----
        for (int it = tid; it < PY * TX; it += 256) {
            const int r = it >> 4;
            const int x = it & 15;
#pragma unroll
            for (int p = 0; p < 2; ++p) {
                float a = 0.f, bq = 0.f, aa = 0.f, bb = 0.f, ab = 0.f;
#pragma unroll
                for (int dx = 0; dx < 9; ++dx) {
                    const float2 v = sIJ[p][r][x + dx];
                    a += v.x; bq += v.y;
                    aa = fmaf(v.x, v.x, aa);
                    bb = fmaf(v.y, v.y, bb);
                    ab = fmaf(v.x, v.y, ab);
                }
                s4m[p][r][x] = make_float4(a, bq, aa, bb);
                s1m[p][r][x] = ab;
            }
        }
        __syncthreads();

        // ---- y-pass + rolling z-update + epilogue, both planes ----
#pragma unroll
        for (int p = 0; p < 2; ++p) {
            float y0 = 0.f, y1 = 0.f, y2 = 0.f, y3 = 0.f, y4 = 0.f;
#pragma unroll
            for (int dy = 0; dy < 9; ++dy) {
                const float4 t = s4m[p][ly + dy][lx];
                y0 += t.x; y1 += t.y; y2 += t.z; y3 += t.w;
                y4 += s1m[p][ly + dy][lx];
            }

            zs0 += y0 - rb0[0]; zs1 += y1 - rb1[0]; zs2 += y2 - rb2[0];
            zs3 += y3 - rb3[0]; zs4 += y4 - rb4[0];
#pragma unroll
            for (int i = 0; i < 8; ++i) {
                rb0[i]=rb0[i+1]; rb1[i]=rb1[i+1]; rb2[i]=rb2[i+1];
                rb3[i]=rb3[i+1]; rb4[i]=rb4[i+1];
            }
            rb0[8]=y0; rb1[8]=y1; rb2[8]=y2; rb3[8]=y3; rb4[8]=y4;

            const int zi = 2 * rnd + p;
            if (zi >= 8) {
                const float inv = 1.0f / 729.0f;
                const float uI = zs0 * inv;
                const float uJ = zs1 * inv;
                const float cross = zs4 - uJ * zs0 - uI * zs1 + uI * uJ * 729.0f;
                const float Ivar  = zs2 - 2.0f * uI * zs0 + uI * uI * 729.0f;
                const float Jvar  = zs3 - 2.0f * uJ * zs1 + uJ * uJ * 729.0f;
                acc += cross * cross / (Ivar * Jvar + 1e-5f);
            }
        }
    }

    // block reduction: wave shuffle then cross-wave via LDS
#pragma unroll
    for (int off = 32; off > 0; off >>= 1) acc += __shfl_down(acc, off);
    __shared__ float wpart[4];
    if ((tid & 63) == 0) wpart[tid >> 6] = acc;
    __syncthreads();
    if (tid == 0) {
        const float s = wpart[0] + wpart[1] + wpart[2] + wpart[3];
        atomicAdd(out, s * (-1.0f / NVOX));
    }
}

extern "C" void kernel_launch(void* const* d_in, const int* in_sizes, int n_in,
                              void* d_out, int out_size, void* d_ws, size_t ws_size,
                              hipStream_t stream)
{
    // setup_inputs order: d_in[0] = y_pred (J), d_in[1] = y_true (I)
    const float* J = (const float*)d_in[0];
    const float* I = (const float*)d_in[1];
    float* out = (float*)d_out;

    ncc_zero<<<dim3(1), dim3(1), 0, stream>>>(out);
    dim3 grid(DSZ / TX, DSZ / TY, 2 * (DSZ / 16));  // 8 x 8 x 16 = 1024 blocks
    ncc_main<<<grid, dim3(256), 0, stream>>>(I, J, out);
}

// Round 3
// 49.798 us; speedup vs baseline: 1.6709x; 1.2406x over previous
//
#include <hip/hip_runtime.h>

#define DSZ 128
#define TX 16
#define TY 16
#define PY 24            // TY + 8 halo
#define NVOX 4194304.0f

__global__ void ncc_zero(float* out) { out[0] = 0.0f; }

__global__ __launch_bounds__(256) void ncc_main(const float* __restrict__ Iin,
                                                const float* __restrict__ Jin,
                                                float* __restrict__ out)
{
    const int tx0 = blockIdx.x * TX;
    const int ty0 = blockIdx.y * TY;
    const int b   = blockIdx.z >> 3;
    const int tz0 = (blockIdx.z & 7) * 16;
    const int tid = threadIdx.x;
    const int lx  = tid & 15;
    const int ly  = tid >> 4;

    const float* __restrict__ Ib = Iin + b * (DSZ * DSZ * DSZ);
    const float* __restrict__ Jb = Jin + b * (DSZ * DSZ * DSZ);

    // x-summed moments only; 4 plane slots (quad-buffer) -> 1 barrier/round.
    // s4m: (sumI,sumJ,sumII,sumJJ). s1v row = 5 float4 = 20 floats of sumIJ.
    __shared__ float4 s4m[4][PY][17];
    __shared__ float4 s1v[4][PY][5];

    // 9-plane rolling z-window, registers only (compile-time indices)
    float rb0[9], rb1[9], rb2[9], rb3[9], rb4[9];
#pragma unroll
    for (int i = 0; i < 9; ++i) { rb0[i]=0.f; rb1[i]=0.f; rb2[i]=0.f; rb3[i]=0.f; rb4[i]=0.f; }
    float zs0=0.f, zs1=0.f, zs2=0.f, zs3=0.f, zs4=0.f;
    float acc = 0.f;

    for (int rnd = 0; rnd < 12; ++rnd) {
        // ---- Phase A: direct-from-global x-pass, 2 planes, 192 active threads
        if (tid < 192) {
            const int p   = (tid >= 96);
            const int t2  = tid - p * 96;
            const int r   = t2 >> 2;       // 0..23  (y-halo row)
            const int xg  = t2 & 3;        // 0..3   (group of 4 x-outputs)
            const int zp  = tz0 + 2 * rnd + p - 4;
            const int gy  = ty0 + r - 4;
            const int gxb = tx0 + 4 * xg - 4;          // 4-aligned
            const bool rowok = ((unsigned)zp < (unsigned)DSZ) &&
                               ((unsigned)gy < (unsigned)DSZ);
            const int zoff = (zp * DSZ + gy) * DSZ;    // only used when rowok

            float vi[12], vj[12];
#pragma unroll
            for (int g = 0; g < 3; ++g) {
                const int gx = gxb + 4 * g;
                float4 va = make_float4(0.f, 0.f, 0.f, 0.f);
                float4 vb = va;
                if (rowok && (unsigned)gx < (unsigned)DSZ) {
                    va = *(const float4*)(Ib + zoff + gx);
                    vb = *(const float4*)(Jb + zoff + gx);
                }
                vi[4*g+0]=va.x; vi[4*g+1]=va.y; vi[4*g+2]=va.z; vi[4*g+3]=va.w;
                vj[4*g+0]=vb.x; vj[4*g+1]=vb.y; vj[4*g+2]=vb.z; vj[4*g+3]=vb.w;
            }

            // shared core v3..v8, then rolling for the 4 windows
            float wI=0.f, wJ=0.f, wII=0.f, wJJ=0.f, wIJ=0.f;
#pragma unroll
            for (int k = 3; k < 9; ++k) {
                wI += vi[k]; wJ += vj[k];
                wII = fmaf(vi[k], vi[k], wII);
                wJJ = fmaf(vj[k], vj[k], wJJ);
                wIJ = fmaf(vi[k], vj[k], wIJ);
            }
#pragma unroll
            for (int k = 0; k < 3; ++k) {
                wI += vi[k]; wJ += vj[k];
                wII = fmaf(vi[k], vi[k], wII);
                wJJ = fmaf(vj[k], vj[k], wJJ);
                wIJ = fmaf(vi[k], vj[k], wIJ);
            }
            const int sl = (rnd & 1) * 2 + p;
            float mIJ[4];
            s4m[sl][r][4*xg] = make_float4(wI, wJ, wII, wJJ);
            mIJ[0] = wIJ;
#pragma unroll
            for (int j = 1; j < 4; ++j) {
                const float ai = vi[8+j], aj = vj[8+j];   // entering
                const float di = vi[j-1], dj = vj[j-1];   // leaving
                wI += ai - di; wJ += aj - dj;
                wII += fmaf(ai, ai, -di * di);
                wJJ += fmaf(aj, aj, -dj * dj);
                wIJ += fmaf(ai, aj, -di * dj);
                s4m[sl][r][4*xg + j] = make_float4(wI, wJ, wII, wJJ);
                mIJ[j] = wIJ;
            }
            s1v[sl][r][xg] = make_float4(mIJ[0], mIJ[1], mIJ[2], mIJ[3]);
        }
        __syncthreads();

        // ---- Phase B: y-pass + rolling z-update + epilogue, both planes ----
#pragma unroll
        for (int p = 0; p < 2; ++p) {
            const int sl = (rnd & 1) * 2 + p;
            float y0=0.f, y1=0.f, y2=0.f, y3=0.f, y4=0.f;
#pragma unroll
            for (int dy = 0; dy < 9; ++dy) {
                const float4 t = s4m[sl][ly + dy][lx];
                y0 += t.x; y1 += t.y; y2 += t.z; y3 += t.w;
                y4 += ((const float*)&s1v[sl][ly + dy][0])[lx];
            }

            zs0 += y0 - rb0[0]; zs1 += y1 - rb1[0]; zs2 += y2 - rb2[0];
            zs3 += y3 - rb3[0]; zs4 += y4 - rb4[0];
#pragma unroll
            for (int i = 0; i < 8; ++i) {
                rb0[i]=rb0[i+1]; rb1[i]=rb1[i+1]; rb2[i]=rb2[i+1];
                rb3[i]=rb3[i+1]; rb4[i]=rb4[i+1];
            }
            rb0[8]=y0; rb1[8]=y1; rb2[8]=y2; rb3[8]=y3; rb4[8]=y4;

            const int zi = 2 * rnd + p;
            if (zi >= 8) {
                const float inv = 1.0f / 729.0f;
                const float uI = zs0 * inv;
                const float uJ = zs1 * inv;
                const float cross = zs4 - uJ * zs0 - uI * zs1 + uI * uJ * 729.0f;
                const float Ivar  = zs2 - 2.0f * uI * zs0 + uI * uI * 729.0f;
                const float Jvar  = zs3 - 2.0f * uJ * zs1 + uJ * uJ * 729.0f;
                acc += cross * cross / (Ivar * Jvar + 1e-5f);
            }
        }
    }

    // block reduction: wave shuffle then cross-wave via LDS
#pragma unroll
    for (int off = 32; off > 0; off >>= 1) acc += __shfl_down(acc, off);
    __shared__ float wpart[4];
    if ((tid & 63) == 0) wpart[tid >> 6] = acc;
    __syncthreads();
    if (tid == 0) {
        const float s = wpart[0] + wpart[1] + wpart[2] + wpart[3];
        atomicAdd(out, s * (-1.0f / NVOX));
    }
}

extern "C" void kernel_launch(void* const* d_in, const int* in_sizes, int n_in,
                              void* d_out, int out_size, void* d_ws, size_t ws_size,
                              hipStream_t stream)
{
    // setup_inputs order: d_in[0] = y_pred (J), d_in[1] = y_true (I)
    const float* J = (const float*)d_in[0];
    const float* I = (const float*)d_in[1];
    float* out = (float*)d_out;

    ncc_zero<<<dim3(1), dim3(1), 0, stream>>>(out);
    dim3 grid(DSZ / TX, DSZ / TY, 2 * (DSZ / 16));  // 8 x 8 x 16 = 1024 blocks
    ncc_main<<<grid, dim3(256), 0, stream>>>(I, J, out);
}